// Round 4
// baseline (559.394 us; speedup 1.0000x reference)
//
#include <hip/hip_runtime.h>
#include <stdint.h>

typedef __bf16 bf16x8 __attribute__((ext_vector_type(8)));
typedef float f32x16 __attribute__((ext_vector_type(16)));

__device__ __forceinline__ unsigned short f2bf(float f) {
  unsigned u = __float_as_uint(f);
  u += 0x7FFF + ((u >> 16) & 1);   // round-to-nearest-even
  return (unsigned short)(u >> 16);
}
__device__ __forceinline__ float bf2f(unsigned short h) {
  return __uint_as_float(((unsigned)h) << 16);
}

// ---------------- fp32 -> bf16 cast, 4 elems/thread ----------------
__global__ __launch_bounds__(256) void cast_kernel(const float* __restrict__ in,
                                                   unsigned short* __restrict__ out,
                                                   int n4) {
  int i = blockIdx.x * 256 + threadIdx.x;
  if (i >= n4) return;
  float4 v = reinterpret_cast<const float4*>(in)[i];
  ushort4 o;
  o.x = f2bf(v.x); o.y = f2bf(v.y); o.z = f2bf(v.z); o.w = f2bf(v.w);
  reinterpret_cast<ushort4*>(out)[i] = o;
}

// ---------------- GEMM-BT: C[m][n] = sum_k A[m][k]*B[n][k] (+bias[n]) ----------------
// A,B bf16, K-contiguous rows. 128x128 tile, BK=64, 4 waves of 2x2 32x32x16 MFMA.
// Register-staged double-buffered pipeline (R3 showed latency-exposure bound:
// global_load_lds forces vmcnt(0) drain at each barrier with no overlap):
//   iter k: ds_write buf[k+1] from regs; issue global loads tile k+2 -> regs;
//           compute buf[k]; one __syncthreads().
// Global-load latency for tile k+2 is hidden behind compute of tiles k and k+1.
// LDS rows 128 B; 16 B chunks XOR-swizzled by (row&7) for bank spread.
template<int OUT_BF16>
__global__ __launch_bounds__(256, 2) void gemm_bt(
    const unsigned short* __restrict__ A, long lda, long strideA,
    const unsigned short* __restrict__ B, long ldb, long strideB,
    void* __restrict__ Cv, long ldc, long strideC,
    const float* __restrict__ bias, int K) {
  __shared__ unsigned short sA[2][128 * 64];
  __shared__ unsigned short sB[2][128 * 64];
  const int t = threadIdx.x;
  const int lane = t & 63;
  const int wave = t >> 6;

  const unsigned short* Ab = A + (size_t)blockIdx.z * strideA + (size_t)blockIdx.y * 128 * lda;
  const unsigned short* Bb = B + (size_t)blockIdx.z * strideB + (size_t)blockIdx.x * 128 * ldb;

  // staging assignment: thread t -> rows r0=t>>2 and r0+64, quarter q=t&3.
  // chunks per row: q and q+4 (16 B each). Global: 64B-contiguous per 4 lanes.
  const int r0 = t >> 2;
  const int q = t & 3;
  const unsigned short* aptr = Ab + (size_t)r0 * lda + q * 8;
  const unsigned short* bptr = Bb + (size_t)r0 * ldb + q * 8;
  const int sw = r0 & 7;  // (r0+64)&7 == r0&7
  int woff[4];
  woff[0] = r0 * 128 + ((q ^ sw) * 16);
  woff[1] = r0 * 128 + (((q + 4) ^ sw) * 16);
  woff[2] = (r0 + 64) * 128 + ((q ^ sw) * 16);
  woff[3] = (r0 + 64) * 128 + (((q + 4) ^ sw) * 16);

  uint4 ra[4], rb[4];
#define LOAD_TILE(k0)                                                              \
  {                                                                                \
    ra[0] = *reinterpret_cast<const uint4*>(aptr + (k0));                          \
    ra[1] = *reinterpret_cast<const uint4*>(aptr + (k0) + 32);                     \
    ra[2] = *reinterpret_cast<const uint4*>(aptr + 64 * lda + (k0));               \
    ra[3] = *reinterpret_cast<const uint4*>(aptr + 64 * lda + (k0) + 32);          \
    rb[0] = *reinterpret_cast<const uint4*>(bptr + (k0));                          \
    rb[1] = *reinterpret_cast<const uint4*>(bptr + (k0) + 32);                     \
    rb[2] = *reinterpret_cast<const uint4*>(bptr + 64 * ldb + (k0));               \
    rb[3] = *reinterpret_cast<const uint4*>(bptr + 64 * ldb + (k0) + 32);          \
  }
#define STORE_TILE(buf)                                                            \
  {                                                                                \
    char* ba = (char*)&sA[buf][0];                                                 \
    char* bb = (char*)&sB[buf][0];                                                 \
    *reinterpret_cast<uint4*>(ba + woff[0]) = ra[0];                               \
    *reinterpret_cast<uint4*>(ba + woff[1]) = ra[1];                               \
    *reinterpret_cast<uint4*>(ba + woff[2]) = ra[2];                               \
    *reinterpret_cast<uint4*>(ba + woff[3]) = ra[3];                               \
    *reinterpret_cast<uint4*>(bb + woff[0]) = rb[0];                               \
    *reinterpret_cast<uint4*>(bb + woff[1]) = rb[1];                               \
    *reinterpret_cast<uint4*>(bb + woff[2]) = rb[2];                               \
    *reinterpret_cast<uint4*>(bb + woff[3]) = rb[3];                               \
  }

  f32x16 acc[2][2];
#pragma unroll
  for (int i = 0; i < 2; i++)
#pragma unroll
    for (int j = 0; j < 2; j++)
#pragma unroll
      for (int r = 0; r < 16; r++) acc[i][j][r] = 0.f;

  const int wm = (wave >> 1) * 64;
  const int wn = (wave & 1) * 64;
  const int r31 = lane & 31;
  const int half = lane >> 5;            // k-half within 16
  const int swz = r31 & 7;               // matches write swizzle: row&7 == r31&7

  int offA[2][4], offB[2][4];
#pragma unroll
  for (int i = 0; i < 2; i++)
#pragma unroll
    for (int s = 0; s < 4; s++) {
      offA[i][s] = (wm + i * 32 + r31) * 128 + (((2 * s + half) ^ swz) * 16);
      offB[i][s] = (wn + i * 32 + r31) * 128 + (((2 * s + half) ^ swz) * 16);
    }

  const int niter = K >> 6;
  LOAD_TILE(0);
  STORE_TILE(0);
  LOAD_TILE(64);
  __syncthreads();

  for (int k = 0; k < niter; k++) {
    const int cur = k & 1;
    if (k + 1 < niter) STORE_TILE(cur ^ 1);   // tile k+1 regs -> other buffer
    if (k + 2 < niter) LOAD_TILE((k + 2) << 6);  // prefetch tile k+2 -> regs
    const char* cA = (const char*)&sA[cur][0];
    const char* cB = (const char*)&sB[cur][0];
#pragma unroll
    for (int s = 0; s < 4; s++) {
      bf16x8 af[2], bfv[2];
#pragma unroll
      for (int i = 0; i < 2; i++) {
        af[i]  = *reinterpret_cast<const bf16x8*>(cA + offA[i][s]);
        bfv[i] = *reinterpret_cast<const bf16x8*>(cB + offB[i][s]);
      }
#pragma unroll
      for (int i = 0; i < 2; i++)
#pragma unroll
        for (int j = 0; j < 2; j++)
          acc[i][j] = __builtin_amdgcn_mfma_f32_32x32x16_bf16(af[i], bfv[j], acc[i][j], 0, 0, 0);
    }
    __syncthreads();
  }

  // epilogue: 32x32 C/D layout col=lane&31, row=(reg&3)+8*(reg>>2)+4*(lane>>5)
#pragma unroll
  for (int i = 0; i < 2; i++) {
    int gmb = blockIdx.y * 128 + wm + i * 32;
#pragma unroll
    for (int j = 0; j < 2; j++) {
      int gn = blockIdx.x * 128 + wn + j * 32 + r31;
      float bv = bias ? bias[gn] : 0.0f;
#pragma unroll
      for (int r = 0; r < 16; r++) {
        int row = (r & 3) + 8 * (r >> 2) + 4 * half;
        float val = acc[i][j][r] + bv;
        size_t off = (size_t)blockIdx.z * strideC + (size_t)(gmb + row) * ldc + gn;
        if (OUT_BF16)
          ((unsigned short*)Cv)[off] = f2bf(val);
        else
          ((float*)Cv)[off] = val;
      }
    }
  }
#undef LOAD_TILE
#undef STORE_TILE
}

// ---------------- transpose V[b][s][d] -> Vt[b][d][s], bf16 ----------------
__global__ __launch_bounds__(256) void transpose_v(const unsigned short* __restrict__ qkv,
                                                   unsigned short* __restrict__ vt) {
  __shared__ unsigned short tile[64][68];
  int t = threadIdx.x;
  int s0 = blockIdx.x * 64, d0 = blockIdx.y * 64, b = blockIdx.z;
  const unsigned short* V = qkv + (size_t)b * 2048 * 3072 + 2048;
  unsigned short* Vt = vt + (size_t)b * 1024 * 2048;
  int r = t >> 4, c = (t & 15) * 4;
#pragma unroll
  for (int i = 0; i < 4; i++) {
    int s = r + i * 16;
    ushort4 v4 = *reinterpret_cast<const ushort4*>(&V[(size_t)(s0 + s) * 3072 + d0 + c]);
    tile[s][c] = v4.x; tile[s][c + 1] = v4.y; tile[s][c + 2] = v4.z; tile[s][c + 3] = v4.w;
  }
  __syncthreads();
#pragma unroll
  for (int i = 0; i < 4; i++) {
    int d = r + i * 16;
    ushort4 o;
    o.x = tile[c][d]; o.y = tile[c + 1][d]; o.z = tile[c + 2][d]; o.w = tile[c + 3][d];
    *reinterpret_cast<ushort4*>(&Vt[(size_t)(d0 + d) * 2048 + s0 + c]) = o;
  }
}

// ---------------- in-place row softmax over bf16 scores ----------------
// ref: scores = where(mask==0, -1e20, scores); softmax(scores / sqrt(1024))
__global__ __launch_bounds__(256) void softmax_kernel(unsigned short* __restrict__ P,
                                                      const int* __restrict__ mask) {
  __shared__ float red[8];
  const int S = 2048;
  int row = blockIdx.x;
  int b = row >> 11;
  unsigned short* prow = P + (size_t)row * S;
  const int* mrow = mask + (size_t)b * S;
  int t = threadIdx.x;
  int base = t * 8;
  uint4 raw = *reinterpret_cast<const uint4*>(&prow[base]);
  int4 m0 = *reinterpret_cast<const int4*>(&mrow[base]);
  int4 m1 = *reinterpret_cast<const int4*>(&mrow[base + 4]);
  unsigned short us[8];
  us[0] = raw.x & 0xffff; us[1] = raw.x >> 16;
  us[2] = raw.y & 0xffff; us[3] = raw.y >> 16;
  us[4] = raw.z & 0xffff; us[5] = raw.z >> 16;
  us[6] = raw.w & 0xffff; us[7] = raw.w >> 16;
  int mk[8] = {m0.x, m0.y, m0.z, m0.w, m1.x, m1.y, m1.z, m1.w};
  float l[8];
  float mx = -3.4e38f;
#pragma unroll
  for (int j = 0; j < 8; j++) {
    float v = bf2f(us[j]);
    v = (mk[j] == 0) ? -1e20f : v;   // mask BEFORE scaling, per reference
    l[j] = v * 0.03125f;             // 1/sqrt(1024)
    mx = fmaxf(mx, l[j]);
  }
#pragma unroll
  for (int o = 32; o >= 1; o >>= 1) mx = fmaxf(mx, __shfl_xor(mx, o, 64));
  if ((t & 63) == 0) red[t >> 6] = mx;
  __syncthreads();
  mx = fmaxf(fmaxf(red[0], red[1]), fmaxf(red[2], red[3]));
  float e[8], s = 0.f;
#pragma unroll
  for (int j = 0; j < 8; j++) { e[j] = __expf(l[j] - mx); s += e[j]; }
#pragma unroll
  for (int o = 32; o >= 1; o >>= 1) s += __shfl_xor(s, o, 64);
  if ((t & 63) == 0) red[4 + (t >> 6)] = s;
  __syncthreads();
  s = red[4] + red[5] + red[6] + red[7];
  float inv = 1.0f / s;
  unsigned short eo[8];
#pragma unroll
  for (int j = 0; j < 8; j++) eo[j] = f2bf(e[j] * inv);
  uint4 outv;
  outv.x = eo[0] | ((unsigned)eo[1] << 16);
  outv.y = eo[2] | ((unsigned)eo[3] << 16);
  outv.z = eo[4] | ((unsigned)eo[5] << 16);
  outv.w = eo[6] | ((unsigned)eo[7] << 16);
  *reinterpret_cast<uint4*>(&prow[base]) = outv;
}

extern "C" void kernel_launch(void* const* d_in, const int* in_sizes, int n_in,
                              void* d_out, int out_size, void* d_ws, size_t ws_size,
                              hipStream_t stream) {
  const float* X = (const float*)d_in[0];
  const int* mask = (const int*)d_in[1];
  const float* W_in = (const float*)d_in[2];
  const float* b_in = (const float*)d_in[3];
  const float* W_out = (const float*)d_in[4];
  const float* b_out = (const float*)d_in[5];
  float* out = (float*)d_out;

  const int S = 2048, D = 1024;  // B=4 fixed below via grids
  // workspace layout (bytes):
  //   Xb  [8192x1024] bf16  16777216   (reused as Ob after GEMM1)
  //   Wib [3072x1024] bf16   6291456
  //   Wob [1024x1024] bf16   2097152
  //   QKV [8192x3072] bf16  50331648
  //   P   [4x2048x2048] bf16 33554432  (scores, softmaxed in place)
  //   Vt  [4x1024x2048] bf16 16777216   -> total 125829120
  char* w = (char*)d_ws;
  unsigned short* Xb  = (unsigned short*)w;
  unsigned short* Wib = (unsigned short*)(w + 16777216);
  unsigned short* Wob = (unsigned short*)(w + 16777216 + 6291456);
  unsigned short* QKV = (unsigned short*)(w + 16777216 + 6291456 + 2097152);
  unsigned short* P   = (unsigned short*)(w + 16777216 + 6291456 + 2097152 + 50331648);
  unsigned short* Vt  = (unsigned short*)(w + 16777216 + 6291456 + 2097152 + 50331648 + 33554432);
  unsigned short* Ob  = Xb;

  cast_kernel<<<8192, 256, 0, stream>>>(X, Xb, 2097152);
  cast_kernel<<<3072, 256, 0, stream>>>(W_in, Wib, 786432);
  cast_kernel<<<1024, 256, 0, stream>>>(W_out, Wob, 262144);

  // QKV = Xb @ W_in^T + b_in   [8192 x 3072] bf16
  gemm_bt<1><<<dim3(24, 64, 1), 256, 0, stream>>>(Xb, D, 0, Wib, D, 0,
                                                  QKV, 3 * D, 0, b_in, D);
  // Vt[b][d][s] = V[b][s][d]
  transpose_v<<<dim3(32, 16, 4), 256, 0, stream>>>(QKV, Vt);
  // scores[b] = Q[b] @ K[b]^T  [2048 x 2048] bf16 (raw, mask/scale in softmax)
  gemm_bt<1><<<dim3(16, 16, 4), 256, 0, stream>>>(QKV, 3 * D, (long)S * 3 * D,
                                                  QKV + D, 3 * D, (long)S * 3 * D,
                                                  P, S, (long)S * S, nullptr, D);
  softmax_kernel<<<8192, 256, 0, stream>>>(P, mask);
  // O[b] = P[b] @ Vt[b]^T      [2048 x 1024] bf16
  gemm_bt<1><<<dim3(8, 16, 4), 256, 0, stream>>>(P, S, (long)S * S,
                                                 Vt, S, (long)D * S,
                                                 Ob, D, (long)S * D, nullptr, S);
  // out = O @ W_out^T + b_out  [8192 x 1024] fp32
  gemm_bt<0><<<dim3(8, 64, 1), 256, 0, stream>>>(Ob, D, 0, Wob, D, 0,
                                                 out, D, 0, b_out, D);
}

// Round 5
// 314.396 us; speedup vs baseline: 1.7793x; 1.7793x over previous
//
#include <hip/hip_runtime.h>
#include <stdint.h>

#define AS1 __attribute__((address_space(1)))
#define AS3 __attribute__((address_space(3)))

typedef __bf16 bf16x8 __attribute__((ext_vector_type(8)));
typedef float f32x16 __attribute__((ext_vector_type(16)));

__device__ __forceinline__ unsigned short f2bf(float f) {
  unsigned u = __float_as_uint(f);
  u += 0x7FFF + ((u >> 16) & 1);   // round-to-nearest-even
  return (unsigned short)(u >> 16);
}
__device__ __forceinline__ float bf2f(unsigned short h) {
  return __uint_as_float(((unsigned)h) << 16);
}

// ---------------- fp32 -> bf16 cast, 4 elems/thread ----------------
__global__ __launch_bounds__(256) void cast_kernel(const float* __restrict__ in,
                                                   unsigned short* __restrict__ out,
                                                   int n4) {
  int i = blockIdx.x * 256 + threadIdx.x;
  if (i >= n4) return;
  float4 v = reinterpret_cast<const float4*>(in)[i];
  ushort4 o;
  o.x = f2bf(v.x); o.y = f2bf(v.y); o.z = f2bf(v.z); o.w = f2bf(v.w);
  reinterpret_cast<ushort4*>(out)[i] = o;
}

// ---------------- GEMM-BT 128x128 (R3-proven): C[m][n] = sum_k A[m][k]*B[n][k] ----------------
// BK=64, 4 waves of 2x2 32x32x16 MFMA, global_load_lds staging, XOR-8 chunk swizzle.
template<int OUT_BF16>
__global__ __launch_bounds__(256, 2) void gemm_bt128(
    const unsigned short* __restrict__ A, long lda, long strideA,
    const unsigned short* __restrict__ B, long ldb, long strideB,
    void* __restrict__ Cv, long ldc, long strideC,
    const float* __restrict__ bias, int K) {
  __shared__ unsigned short sA[128 * 64];
  __shared__ unsigned short sB[128 * 64];
  const int t = threadIdx.x;
  const int lane = t & 63;
  const int wave = t >> 6;

  const unsigned short* Ab = A + (size_t)blockIdx.z * strideA + (size_t)blockIdx.y * 128 * lda;
  const unsigned short* Bb = B + (size_t)blockIdx.z * strideB + (size_t)blockIdx.x * 128 * ldb;

  const int srow = t >> 3;
  const int schunk = (t & 7) ^ (srow & 7);
  const unsigned short* aptr = Ab + (size_t)srow * lda + schunk * 8;
  const unsigned short* bptr = Bb + (size_t)srow * ldb + schunk * 8;
  char* ldsA0 = (char*)&sA[0] + wave * 1024;
  char* ldsB0 = (char*)&sB[0] + wave * 1024;

  f32x16 acc[2][2];
#pragma unroll
  for (int i = 0; i < 2; i++)
#pragma unroll
    for (int j = 0; j < 2; j++)
#pragma unroll
      for (int r = 0; r < 16; r++) acc[i][j][r] = 0.f;

  const int wm = (wave >> 1) * 64;
  const int wn = (wave & 1) * 64;
  const int r31 = lane & 31;
  const int half = lane >> 5;
  const int swz = r31 & 7;

  int offA[2][4], offB[2][4];
#pragma unroll
  for (int i = 0; i < 2; i++)
#pragma unroll
    for (int s = 0; s < 4; s++) {
      offA[i][s] = (wm + i * 32 + r31) * 128 + (((2 * s + half) ^ swz) * 16);
      offB[i][s] = (wn + i * 32 + r31) * 128 + (((2 * s + half) ^ swz) * 16);
    }

  for (int k0 = 0; k0 < K; k0 += 64) {
    __syncthreads();
#pragma unroll
    for (int o = 0; o < 4; o++) {
      __builtin_amdgcn_global_load_lds((AS1 void*)(aptr + (size_t)o * 32 * lda + k0),
                                       (AS3 void*)(ldsA0 + o * 4096), 16, 0, 0);
      __builtin_amdgcn_global_load_lds((AS1 void*)(bptr + (size_t)o * 32 * ldb + k0),
                                       (AS3 void*)(ldsB0 + o * 4096), 16, 0, 0);
    }
    __syncthreads();
#pragma unroll
    for (int s = 0; s < 4; s++) {
      bf16x8 af[2], bfv[2];
#pragma unroll
      for (int i = 0; i < 2; i++) {
        af[i]  = *reinterpret_cast<const bf16x8*>((const char*)sA + offA[i][s]);
        bfv[i] = *reinterpret_cast<const bf16x8*>((const char*)sB + offB[i][s]);
      }
#pragma unroll
      for (int i = 0; i < 2; i++)
#pragma unroll
        for (int j = 0; j < 2; j++)
          acc[i][j] = __builtin_amdgcn_mfma_f32_32x32x16_bf16(af[i], bfv[j], acc[i][j], 0, 0, 0);
    }
  }

#pragma unroll
  for (int i = 0; i < 2; i++) {
    int gmb = blockIdx.y * 128 + wm + i * 32;
#pragma unroll
    for (int j = 0; j < 2; j++) {
      int gn = blockIdx.x * 128 + wn + j * 32 + r31;
      float bv = bias ? bias[gn] : 0.0f;
#pragma unroll
      for (int r = 0; r < 16; r++) {
        int row = (r & 3) + 8 * (r >> 2) + 4 * half;
        float val = acc[i][j][r] + bv;
        size_t off = (size_t)blockIdx.z * strideC + (size_t)(gmb + row) * ldc + gn;
        if (OUT_BF16)
          ((unsigned short*)Cv)[off] = f2bf(val);
        else
          ((float*)Cv)[off] = val;
      }
    }
  }
}

// ---------------- GEMM-BT 128x256: wave tile 64x128 (2x4 of 32x32x16) ----------------
// Higher arithmetic intensity: 6 ds_read_b128 per 8 MFMA (0.75 KB/MFMA vs 1.0 in
// the 128x128 kernel) — attacks the LDS read-BW ceiling that capped MfmaUtil at 30%.
// 32 MFMA (256 cyc) per barrier pair. LDS 48 KB -> 3 blocks/CU.
template<int OUT_BF16>
__global__ __launch_bounds__(256, 2) void gemm_bt256(
    const unsigned short* __restrict__ A, long lda, long strideA,
    const unsigned short* __restrict__ B, long ldb, long strideB,
    void* __restrict__ Cv, long ldc, long strideC,
    const float* __restrict__ bias, int K) {
  __shared__ unsigned short sA[128 * 64];
  __shared__ unsigned short sB[256 * 64];
  const int t = threadIdx.x;
  const int lane = t & 63;
  const int wave = t >> 6;

  const unsigned short* Ab = A + (size_t)blockIdx.z * strideA + (size_t)blockIdx.y * 128 * lda;
  const unsigned short* Bb = B + (size_t)blockIdx.z * strideB + (size_t)blockIdx.x * 256 * ldb;

  // staging: op o covers rows o*32..o*32+31; thread t -> row t>>3, chunk (t&7)^(row&7)
  const int srow = t >> 3;
  const int schunk = (t & 7) ^ (srow & 7);
  const unsigned short* aptr = Ab + (size_t)srow * lda + schunk * 8;
  const unsigned short* bptr = Bb + (size_t)srow * ldb + schunk * 8;
  char* ldsA0 = (char*)&sA[0] + wave * 1024;
  char* ldsB0 = (char*)&sB[0] + wave * 1024;

  f32x16 acc[2][4];
#pragma unroll
  for (int i = 0; i < 2; i++)
#pragma unroll
    for (int j = 0; j < 4; j++)
#pragma unroll
      for (int r = 0; r < 16; r++) acc[i][j][r] = 0.f;

  const int wm = (wave >> 1) * 64;    // 0 or 64 within 128 rows
  const int wn = (wave & 1) * 128;    // 0 or 128 within 256 cols
  const int r31 = lane & 31;
  const int half = lane >> 5;
  const int swz = r31 & 7;

  int offA[2][4], offB[4][4];
#pragma unroll
  for (int s = 0; s < 4; s++) {
#pragma unroll
    for (int i = 0; i < 2; i++)
      offA[i][s] = (wm + i * 32 + r31) * 128 + (((2 * s + half) ^ swz) * 16);
#pragma unroll
    for (int j = 0; j < 4; j++)
      offB[j][s] = (wn + j * 32 + r31) * 128 + (((2 * s + half) ^ swz) * 16);
  }

  for (int k0 = 0; k0 < K; k0 += 64) {
    __syncthreads();
#pragma unroll
    for (int o = 0; o < 4; o++)
      __builtin_amdgcn_global_load_lds((AS1 void*)(aptr + (size_t)o * 32 * lda + k0),
                                       (AS3 void*)(ldsA0 + o * 4096), 16, 0, 0);
#pragma unroll
    for (int o = 0; o < 8; o++)
      __builtin_amdgcn_global_load_lds((AS1 void*)(bptr + (size_t)o * 32 * ldb + k0),
                                       (AS3 void*)(ldsB0 + o * 4096), 16, 0, 0);
    __syncthreads();
#pragma unroll
    for (int s = 0; s < 4; s++) {
      bf16x8 af[2], bfv[4];
#pragma unroll
      for (int i = 0; i < 2; i++)
        af[i] = *reinterpret_cast<const bf16x8*>((const char*)sA + offA[i][s]);
#pragma unroll
      for (int j = 0; j < 4; j++)
        bfv[j] = *reinterpret_cast<const bf16x8*>((const char*)sB + offB[j][s]);
#pragma unroll
      for (int i = 0; i < 2; i++)
#pragma unroll
        for (int j = 0; j < 4; j++)
          acc[i][j] = __builtin_amdgcn_mfma_f32_32x32x16_bf16(af[i], bfv[j], acc[i][j], 0, 0, 0);
    }
  }

#pragma unroll
  for (int i = 0; i < 2; i++) {
    int gmb = blockIdx.y * 128 + wm + i * 32;
#pragma unroll
    for (int j = 0; j < 4; j++) {
      int gn = blockIdx.x * 256 + wn + j * 32 + r31;
      float bv = bias ? bias[gn] : 0.0f;
#pragma unroll
      for (int r = 0; r < 16; r++) {
        int row = (r & 3) + 8 * (r >> 2) + 4 * half;
        float val = acc[i][j][r] + bv;
        size_t off = (size_t)blockIdx.z * strideC + (size_t)(gmb + row) * ldc + gn;
        if (OUT_BF16)
          ((unsigned short*)Cv)[off] = f2bf(val);
        else
          ((float*)Cv)[off] = val;
      }
    }
  }
}

// ---------------- transpose V[b][s][d] -> Vt[b][d][s], bf16 ----------------
__global__ __launch_bounds__(256) void transpose_v(const unsigned short* __restrict__ qkv,
                                                   unsigned short* __restrict__ vt) {
  __shared__ unsigned short tile[64][68];
  int t = threadIdx.x;
  int s0 = blockIdx.x * 64, d0 = blockIdx.y * 64, b = blockIdx.z;
  const unsigned short* V = qkv + (size_t)b * 2048 * 3072 + 2048;
  unsigned short* Vt = vt + (size_t)b * 1024 * 2048;
  int r = t >> 4, c = (t & 15) * 4;
#pragma unroll
  for (int i = 0; i < 4; i++) {
    int s = r + i * 16;
    ushort4 v4 = *reinterpret_cast<const ushort4*>(&V[(size_t)(s0 + s) * 3072 + d0 + c]);
    tile[s][c] = v4.x; tile[s][c + 1] = v4.y; tile[s][c + 2] = v4.z; tile[s][c + 3] = v4.w;
  }
  __syncthreads();
#pragma unroll
  for (int i = 0; i < 4; i++) {
    int d = r + i * 16;
    ushort4 o;
    o.x = tile[c][d]; o.y = tile[c + 1][d]; o.z = tile[c + 2][d]; o.w = tile[c + 3][d];
    *reinterpret_cast<ushort4*>(&Vt[(size_t)(d0 + d) * 2048 + s0 + c]) = o;
  }
}

// ---------------- in-place row softmax over bf16 scores ----------------
__global__ __launch_bounds__(256) void softmax_kernel(unsigned short* __restrict__ P,
                                                      const int* __restrict__ mask) {
  __shared__ float red[8];
  const int S = 2048;
  int row = blockIdx.x;
  int b = row >> 11;
  unsigned short* prow = P + (size_t)row * S;
  const int* mrow = mask + (size_t)b * S;
  int t = threadIdx.x;
  int base = t * 8;
  uint4 raw = *reinterpret_cast<const uint4*>(&prow[base]);
  int4 m0 = *reinterpret_cast<const int4*>(&mrow[base]);
  int4 m1 = *reinterpret_cast<const int4*>(&mrow[base + 4]);
  unsigned short us[8];
  us[0] = raw.x & 0xffff; us[1] = raw.x >> 16;
  us[2] = raw.y & 0xffff; us[3] = raw.y >> 16;
  us[4] = raw.z & 0xffff; us[5] = raw.z >> 16;
  us[6] = raw.w & 0xffff; us[7] = raw.w >> 16;
  int mk[8] = {m0.x, m0.y, m0.z, m0.w, m1.x, m1.y, m1.z, m1.w};
  float l[8];
  float mx = -3.4e38f;
#pragma unroll
  for (int j = 0; j < 8; j++) {
    float v = bf2f(us[j]);
    v = (mk[j] == 0) ? -1e20f : v;   // mask BEFORE scaling, per reference
    l[j] = v * 0.03125f;             // 1/sqrt(1024)
    mx = fmaxf(mx, l[j]);
  }
#pragma unroll
  for (int o = 32; o >= 1; o >>= 1) mx = fmaxf(mx, __shfl_xor(mx, o, 64));
  if ((t & 63) == 0) red[t >> 6] = mx;
  __syncthreads();
  mx = fmaxf(fmaxf(red[0], red[1]), fmaxf(red[2], red[3]));
  float e[8], s = 0.f;
#pragma unroll
  for (int j = 0; j < 8; j++) { e[j] = __expf(l[j] - mx); s += e[j]; }
#pragma unroll
  for (int o = 32; o >= 1; o >>= 1) s += __shfl_xor(s, o, 64);
  if ((t & 63) == 0) red[4 + (t >> 6)] = s;
  __syncthreads();
  s = red[4] + red[5] + red[6] + red[7];
  float inv = 1.0f / s;
  unsigned short eo[8];
#pragma unroll
  for (int j = 0; j < 8; j++) eo[j] = f2bf(e[j] * inv);
  uint4 outv;
  outv.x = eo[0] | ((unsigned)eo[1] << 16);
  outv.y = eo[2] | ((unsigned)eo[3] << 16);
  outv.z = eo[4] | ((unsigned)eo[5] << 16);
  outv.w = eo[6] | ((unsigned)eo[7] << 16);
  *reinterpret_cast<uint4*>(&prow[base]) = outv;
}

extern "C" void kernel_launch(void* const* d_in, const int* in_sizes, int n_in,
                              void* d_out, int out_size, void* d_ws, size_t ws_size,
                              hipStream_t stream) {
  const float* X = (const float*)d_in[0];
  const int* mask = (const int*)d_in[1];
  const float* W_in = (const float*)d_in[2];
  const float* b_in = (const float*)d_in[3];
  const float* W_out = (const float*)d_in[4];
  const float* b_out = (const float*)d_in[5];
  float* out = (float*)d_out;

  const int S = 2048, D = 1024;
  char* w = (char*)d_ws;
  unsigned short* Xb  = (unsigned short*)w;
  unsigned short* Wib = (unsigned short*)(w + 16777216);
  unsigned short* Wob = (unsigned short*)(w + 16777216 + 6291456);
  unsigned short* QKV = (unsigned short*)(w + 16777216 + 6291456 + 2097152);
  unsigned short* P   = (unsigned short*)(w + 16777216 + 6291456 + 2097152 + 50331648);
  unsigned short* Vt  = (unsigned short*)(w + 16777216 + 6291456 + 2097152 + 50331648 + 33554432);
  unsigned short* Ob  = Xb;

  cast_kernel<<<8192, 256, 0, stream>>>(X, Xb, 2097152);
  cast_kernel<<<3072, 256, 0, stream>>>(W_in, Wib, 786432);
  cast_kernel<<<1024, 256, 0, stream>>>(W_out, Wob, 262144);

  // QKV = Xb @ W_in^T + b_in   [8192 x 3072] bf16  (128x256 tile: 768 blocks)
  gemm_bt256<1><<<dim3(12, 64, 1), 256, 0, stream>>>(Xb, D, 0, Wib, D, 0,
                                                     QKV, 3 * D, 0, b_in, D);
  // Vt[b][d][s] = V[b][s][d]
  transpose_v<<<dim3(32, 16, 4), 256, 0, stream>>>(QKV, Vt);
  // scores[b] = Q[b] @ K[b]^T  [2048 x 2048] bf16  (128x256 tile: 512 blocks)
  gemm_bt256<1><<<dim3(8, 16, 4), 256, 0, stream>>>(QKV, 3 * D, (long)S * 3 * D,
                                                    QKV + D, 3 * D, (long)S * 3 * D,
                                                    P, S, (long)S * S, nullptr, D);
  softmax_kernel<<<8192, 256, 0, stream>>>(P, mask);
  // O[b] = P[b] @ Vt[b]^T      [2048 x 1024] bf16  (128x128 tile: 512 blocks)
  gemm_bt128<1><<<dim3(8, 16, 4), 256, 0, stream>>>(P, S, (long)S * S,
                                                    Vt, S, (long)D * S,
                                                    Ob, D, (long)S * D, nullptr, S);
  // out = O @ W_out^T + b_out  [8192 x 1024] fp32  (128x128 tile: 512 blocks)
  gemm_bt128<0><<<dim3(8, 64, 1), 256, 0, stream>>>(Ob, D, 0, Wob, D, 0,
                                                    out, D, 0, b_out, D);
}

// Round 6
// 301.158 us; speedup vs baseline: 1.8575x; 1.0440x over previous
//
#include <hip/hip_runtime.h>
#include <stdint.h>

#define AS1 __attribute__((address_space(1)))
#define AS3 __attribute__((address_space(3)))

typedef __bf16 bf16x8 __attribute__((ext_vector_type(8)));
typedef float f32x16 __attribute__((ext_vector_type(16)));

__device__ __forceinline__ unsigned short f2bf(float f) {
  unsigned u = __float_as_uint(f);
  u += 0x7FFF + ((u >> 16) & 1);   // round-to-nearest-even
  return (unsigned short)(u >> 16);
}
__device__ __forceinline__ float bf2f(unsigned short h) {
  return __uint_as_float(((unsigned)h) << 16);
}

// ---------------- merged fp32 -> bf16 cast for X, W_in, W_out ----------------
// Outputs are contiguous in ws (Xb | Wib | Wob), inputs are 3 pointers.
__global__ __launch_bounds__(256) void cast_all_kernel(const float* __restrict__ X,
                                                       const float* __restrict__ Wi,
                                                       const float* __restrict__ Wo,
                                                       unsigned short* __restrict__ out) {
  const int c1 = 2097152;            // X groups of 4
  const int c2 = 786432;             // W_in groups
  const int c3 = 262144;             // W_out groups
  int i = blockIdx.x * 256 + threadIdx.x;
  if (i >= c1 + c2 + c3) return;
  const float* src;
  int j = i;
  if (i < c1) src = X;
  else if (i < c1 + c2) { src = Wi; j = i - c1; }
  else { src = Wo; j = i - c1 - c2; }
  float4 v = reinterpret_cast<const float4*>(src)[j];
  ushort4 o;
  o.x = f2bf(v.x); o.y = f2bf(v.y); o.z = f2bf(v.z); o.w = f2bf(v.w);
  reinterpret_cast<ushort4*>(out)[i] = o;
}

// ---------------- GEMM-BT 128x128 (R3-proven): C[m][n] = sum_k A[m][k]*B[n][k] ----------------
// BK=64, 4 waves of 2x2 32x32x16 MFMA, global_load_lds staging, XOR-8 chunk swizzle.
// Optional bias[n]; optional mask (per-z int[2048]): mask[gn]==0 -> val = -1e20
// (reference applies the mask BEFORE the 1/sqrt(D) scaling, done later in softmax).
template<int OUT_BF16>
__global__ __launch_bounds__(256, 2) void gemm_bt128(
    const unsigned short* __restrict__ A, long lda, long strideA,
    const unsigned short* __restrict__ B, long ldb, long strideB,
    void* __restrict__ Cv, long ldc, long strideC,
    const float* __restrict__ bias, const int* __restrict__ mask, int K) {
  __shared__ unsigned short sA[128 * 64];
  __shared__ unsigned short sB[128 * 64];
  const int t = threadIdx.x;
  const int lane = t & 63;
  const int wave = t >> 6;

  const unsigned short* Ab = A + (size_t)blockIdx.z * strideA + (size_t)blockIdx.y * 128 * lda;
  const unsigned short* Bb = B + (size_t)blockIdx.z * strideB + (size_t)blockIdx.x * 128 * ldb;

  const int srow = t >> 3;
  const int schunk = (t & 7) ^ (srow & 7);
  const unsigned short* aptr = Ab + (size_t)srow * lda + schunk * 8;
  const unsigned short* bptr = Bb + (size_t)srow * ldb + schunk * 8;
  char* ldsA0 = (char*)&sA[0] + wave * 1024;
  char* ldsB0 = (char*)&sB[0] + wave * 1024;

  f32x16 acc[2][2];
#pragma unroll
  for (int i = 0; i < 2; i++)
#pragma unroll
    for (int j = 0; j < 2; j++)
#pragma unroll
      for (int r = 0; r < 16; r++) acc[i][j][r] = 0.f;

  const int wm = (wave >> 1) * 64;
  const int wn = (wave & 1) * 64;
  const int r31 = lane & 31;
  const int half = lane >> 5;
  const int swz = r31 & 7;

  int offA[2][4], offB[2][4];
#pragma unroll
  for (int i = 0; i < 2; i++)
#pragma unroll
    for (int s = 0; s < 4; s++) {
      offA[i][s] = (wm + i * 32 + r31) * 128 + (((2 * s + half) ^ swz) * 16);
      offB[i][s] = (wn + i * 32 + r31) * 128 + (((2 * s + half) ^ swz) * 16);
    }

  for (int k0 = 0; k0 < K; k0 += 64) {
    __syncthreads();
#pragma unroll
    for (int o = 0; o < 4; o++) {
      __builtin_amdgcn_global_load_lds((AS1 void*)(aptr + (size_t)o * 32 * lda + k0),
                                       (AS3 void*)(ldsA0 + o * 4096), 16, 0, 0);
      __builtin_amdgcn_global_load_lds((AS1 void*)(bptr + (size_t)o * 32 * ldb + k0),
                                       (AS3 void*)(ldsB0 + o * 4096), 16, 0, 0);
    }
    __syncthreads();
#pragma unroll
    for (int s = 0; s < 4; s++) {
      bf16x8 af[2], bfv[2];
#pragma unroll
      for (int i = 0; i < 2; i++) {
        af[i]  = *reinterpret_cast<const bf16x8*>((const char*)sA + offA[i][s]);
        bfv[i] = *reinterpret_cast<const bf16x8*>((const char*)sB + offB[i][s]);
      }
#pragma unroll
      for (int i = 0; i < 2; i++)
#pragma unroll
        for (int j = 0; j < 2; j++)
          acc[i][j] = __builtin_amdgcn_mfma_f32_32x32x16_bf16(af[i], bfv[j], acc[i][j], 0, 0, 0);
    }
  }

  const int* mrow = mask ? (mask + (size_t)blockIdx.z * 2048) : nullptr;
#pragma unroll
  for (int i = 0; i < 2; i++) {
    int gmb = blockIdx.y * 128 + wm + i * 32;
#pragma unroll
    for (int j = 0; j < 2; j++) {
      int gn = blockIdx.x * 128 + wn + j * 32 + r31;
      float bv = bias ? bias[gn] : 0.0f;
      bool msk = mrow ? (mrow[gn] == 0) : false;
#pragma unroll
      for (int r = 0; r < 16; r++) {
        int row = (r & 3) + 8 * (r >> 2) + 4 * half;
        float val = acc[i][j][r] + bv;
        if (msk) val = -1e20f;
        size_t off = (size_t)blockIdx.z * strideC + (size_t)(gmb + row) * ldc + gn;
        if (OUT_BF16)
          ((unsigned short*)Cv)[off] = f2bf(val);
        else
          ((float*)Cv)[off] = val;
      }
    }
  }
}

// ---------------- transpose V[b][s][d] -> Vt[b][d][s], bf16 ----------------
__global__ __launch_bounds__(256) void transpose_v(const unsigned short* __restrict__ qkv,
                                                   unsigned short* __restrict__ vt) {
  __shared__ unsigned short tile[64][68];
  int t = threadIdx.x;
  int s0 = blockIdx.x * 64, d0 = blockIdx.y * 64, b = blockIdx.z;
  const unsigned short* V = qkv + (size_t)b * 2048 * 3072 + 2048;
  unsigned short* Vt = vt + (size_t)b * 1024 * 2048;
  int r = t >> 4, c = (t & 15) * 4;
#pragma unroll
  for (int i = 0; i < 4; i++) {
    int s = r + i * 16;
    ushort4 v4 = *reinterpret_cast<const ushort4*>(&V[(size_t)(s0 + s) * 3072 + d0 + c]);
    tile[s][c] = v4.x; tile[s][c + 1] = v4.y; tile[s][c + 2] = v4.z; tile[s][c + 3] = v4.w;
  }
  __syncthreads();
#pragma unroll
  for (int i = 0; i < 4; i++) {
    int d = r + i * 16;
    ushort4 o;
    o.x = tile[c][d]; o.y = tile[c + 1][d]; o.z = tile[c + 2][d]; o.w = tile[c + 3][d];
    *reinterpret_cast<ushort4*>(&Vt[(size_t)(d0 + d) * 2048 + s0 + c]) = o;
  }
}

// ---------------- row softmax, one row per wave (no LDS, no barriers) ----------------
// Input P already masked (-1e20 at masked cols, from the QK^T epilogue).
// softmax(P * 1/sqrt(1024)) in place. Row = 2048 bf16; lane handles 32 elems.
__global__ __launch_bounds__(256) void softmax_kernel(unsigned short* __restrict__ P) {
  const int S = 2048;
  int row = blockIdx.x * 4 + (threadIdx.x >> 6);
  int lane = threadIdx.x & 63;
  unsigned short* prow = P + (size_t)row * S;
  uint4 raw[4];
#pragma unroll
  for (int j = 0; j < 4; j++)
    raw[j] = reinterpret_cast<const uint4*>(prow)[lane + j * 64];
  float v[32];
  float mx = -3.4e38f;
#pragma unroll
  for (int j = 0; j < 4; j++) {
    const unsigned* pw = (const unsigned*)&raw[j];
#pragma unroll
    for (int h = 0; h < 4; h++) {
      float a = bf2f(pw[h] & 0xffff) * 0.03125f;   // 1/sqrt(1024)
      float b = bf2f(pw[h] >> 16) * 0.03125f;
      v[j * 8 + h * 2] = a;
      v[j * 8 + h * 2 + 1] = b;
      mx = fmaxf(mx, fmaxf(a, b));
    }
  }
#pragma unroll
  for (int o = 32; o >= 1; o >>= 1) mx = fmaxf(mx, __shfl_xor(mx, o, 64));
  float s = 0.f;
#pragma unroll
  for (int e = 0; e < 32; e++) { v[e] = __expf(v[e] - mx); s += v[e]; }
#pragma unroll
  for (int o = 32; o >= 1; o >>= 1) s += __shfl_xor(s, o, 64);
  float inv = 1.0f / s;
#pragma unroll
  for (int j = 0; j < 4; j++) {
    uint4 o4;
    unsigned* ow = (unsigned*)&o4;
#pragma unroll
    for (int h = 0; h < 4; h++)
      ow[h] = f2bf(v[j * 8 + h * 2] * inv) |
              ((unsigned)f2bf(v[j * 8 + h * 2 + 1] * inv) << 16);
    reinterpret_cast<uint4*>(prow)[lane + j * 64] = o4;
  }
}

extern "C" void kernel_launch(void* const* d_in, const int* in_sizes, int n_in,
                              void* d_out, int out_size, void* d_ws, size_t ws_size,
                              hipStream_t stream) {
  const float* X = (const float*)d_in[0];
  const int* mask = (const int*)d_in[1];
  const float* W_in = (const float*)d_in[2];
  const float* b_in = (const float*)d_in[3];
  const float* W_out = (const float*)d_in[4];
  const float* b_out = (const float*)d_in[5];
  float* out = (float*)d_out;

  const int S = 2048, D = 1024;
  // ws layout: Xb(16MB) | Wib(6MB) | Wob(2MB) | QKV(48MB) | P(32MB) | Vt(16MB)
  char* w = (char*)d_ws;
  unsigned short* Xb  = (unsigned short*)w;
  unsigned short* Wib = (unsigned short*)(w + 16777216);
  unsigned short* Wob = (unsigned short*)(w + 16777216 + 6291456);
  unsigned short* QKV = (unsigned short*)(w + 16777216 + 6291456 + 2097152);
  unsigned short* P   = (unsigned short*)(w + 16777216 + 6291456 + 2097152 + 50331648);
  unsigned short* Vt  = (unsigned short*)(w + 16777216 + 6291456 + 2097152 + 50331648 + 33554432);
  unsigned short* Ob  = Xb;

  // one merged cast: X, W_in, W_out -> bf16 (outputs contiguous)
  cast_all_kernel<<<12288, 256, 0, stream>>>(X, W_in, W_out, Xb);

  // QKV = Xb @ W_in^T + b_in   [8192 x 3072] bf16
  gemm_bt128<1><<<dim3(24, 64, 1), 256, 0, stream>>>(Xb, D, 0, Wib, D, 0,
                                                     QKV, 3 * D, 0, b_in, nullptr, D);
  // Vt[b][d][s] = V[b][s][d]
  transpose_v<<<dim3(32, 16, 4), 256, 0, stream>>>(QKV, Vt);
  // scores[b] = Q[b] @ K[b]^T, mask applied in epilogue  [2048 x 2048] bf16
  gemm_bt128<1><<<dim3(16, 16, 4), 256, 0, stream>>>(QKV, 3 * D, (long)S * 3 * D,
                                                     QKV + D, 3 * D, (long)S * 3 * D,
                                                     P, S, (long)S * S, nullptr, mask, D);
  // softmax rows in place (one row per wave)
  softmax_kernel<<<2048, 256, 0, stream>>>(P);
  // O[b] = P[b] @ Vt[b]^T      [2048 x 1024] bf16
  gemm_bt128<1><<<dim3(8, 16, 4), 256, 0, stream>>>(P, S, (long)S * S,
                                                    Vt, S, (long)D * S,
                                                    Ob, D, (long)S * D, nullptr, nullptr, S);
  // out = O @ W_out^T + b_out  [8192 x 1024] fp32
  gemm_bt128<0><<<dim3(8, 64, 1), 256, 0, stream>>>(Ob, D, 0, Wob, D, 0,
                                                    out, D, 0, b_out, nullptr, D);
}

// Round 7
// 300.908 us; speedup vs baseline: 1.8590x; 1.0008x over previous
//
#include <hip/hip_runtime.h>
#include <stdint.h>

#define AS1 __attribute__((address_space(1)))
#define AS3 __attribute__((address_space(3)))

typedef __bf16 bf16x8 __attribute__((ext_vector_type(8)));
typedef float f32x16 __attribute__((ext_vector_type(16)));

__device__ __forceinline__ unsigned short f2bf(float f) {
  unsigned u = __float_as_uint(f);
  u += 0x7FFF + ((u >> 16) & 1);   // round-to-nearest-even
  return (unsigned short)(u >> 16);
}
__device__ __forceinline__ float bf2f(unsigned short h) {
  return __uint_as_float(((unsigned)h) << 16);
}

// ---------------- merged fp32 -> bf16 cast for X, W_in, W_out ----------------
__global__ __launch_bounds__(256) void cast_all_kernel(const float* __restrict__ X,
                                                       const float* __restrict__ Wi,
                                                       const float* __restrict__ Wo,
                                                       unsigned short* __restrict__ out) {
  const int c1 = 2097152;            // X groups of 4
  const int c2 = 786432;             // W_in groups
  const int c3 = 262144;             // W_out groups
  int i = blockIdx.x * 256 + threadIdx.x;
  if (i >= c1 + c2 + c3) return;
  const float* src;
  int j = i;
  if (i < c1) src = X;
  else if (i < c1 + c2) { src = Wi; j = i - c1; }
  else { src = Wo; j = i - c1 - c2; }
  float4 v = reinterpret_cast<const float4*>(src)[j];
  ushort4 o;
  o.x = f2bf(v.x); o.y = f2bf(v.y); o.z = f2bf(v.z); o.w = f2bf(v.w);
  reinterpret_cast<ushort4*>(out)[i] = o;
}

// ---------------- GEMM-BT 128x128 (R3-proven core, fused epilogues) ----------------
// C[m][n] = sum_k A[m][k]*B[n][k]. BK=64, 4 waves of 2x2 32x32x16 MFMA,
// global_load_lds staging, XOR-8 chunk swizzle.
// MODE 0: fp32 out, +bias                       (out-proj)
// MODE 1: bf16 out, +bias; blocks bx>=16 write V^T into vt instead (QKV+transpose)
// MODE 2: bf16 out = exp((mask? -1e20 : val) / 32)   (QK^T + mask + unnorm softmax)
// MODE 3: bf16 out = val / rowsum[gm]                 (PV + softmax normalize)
template<int MODE>
__global__ __launch_bounds__(256, 2) void gemm_bt128(
    const unsigned short* __restrict__ A, long lda, long strideA,
    const unsigned short* __restrict__ B, long ldb, long strideB,
    void* __restrict__ Cv, long ldc, long strideC,
    const float* __restrict__ bias, const int* __restrict__ mask,
    const float* __restrict__ sums, unsigned short* __restrict__ vt, int K) {
  __shared__ unsigned short sA[128 * 64];
  __shared__ unsigned short sB[128 * 64];
  const int t = threadIdx.x;
  const int lane = t & 63;
  const int wave = t >> 6;

  const unsigned short* Ab = A + (size_t)blockIdx.z * strideA + (size_t)blockIdx.y * 128 * lda;
  const unsigned short* Bb = B + (size_t)blockIdx.z * strideB + (size_t)blockIdx.x * 128 * ldb;

  const int srow = t >> 3;
  const int schunk = (t & 7) ^ (srow & 7);
  const unsigned short* aptr = Ab + (size_t)srow * lda + schunk * 8;
  const unsigned short* bptr = Bb + (size_t)srow * ldb + schunk * 8;
  char* ldsA0 = (char*)&sA[0] + wave * 1024;
  char* ldsB0 = (char*)&sB[0] + wave * 1024;

  f32x16 acc[2][2];
#pragma unroll
  for (int i = 0; i < 2; i++)
#pragma unroll
    for (int j = 0; j < 2; j++)
#pragma unroll
      for (int r = 0; r < 16; r++) acc[i][j][r] = 0.f;

  const int wm = (wave >> 1) * 64;
  const int wn = (wave & 1) * 64;
  const int r31 = lane & 31;
  const int half = lane >> 5;
  const int swz = r31 & 7;

  int offA[2][4], offB[2][4];
#pragma unroll
  for (int i = 0; i < 2; i++)
#pragma unroll
    for (int s = 0; s < 4; s++) {
      offA[i][s] = (wm + i * 32 + r31) * 128 + (((2 * s + half) ^ swz) * 16);
      offB[i][s] = (wn + i * 32 + r31) * 128 + (((2 * s + half) ^ swz) * 16);
    }

  for (int k0 = 0; k0 < K; k0 += 64) {
    __syncthreads();
#pragma unroll
    for (int o = 0; o < 4; o++) {
      __builtin_amdgcn_global_load_lds((AS1 void*)(aptr + (size_t)o * 32 * lda + k0),
                                       (AS3 void*)(ldsA0 + o * 4096), 16, 0, 0);
      __builtin_amdgcn_global_load_lds((AS1 void*)(bptr + (size_t)o * 32 * ldb + k0),
                                       (AS3 void*)(ldsB0 + o * 4096), 16, 0, 0);
    }
    __syncthreads();
#pragma unroll
    for (int s = 0; s < 4; s++) {
      bf16x8 af[2], bfv[2];
#pragma unroll
      for (int i = 0; i < 2; i++) {
        af[i]  = *reinterpret_cast<const bf16x8*>((const char*)sA + offA[i][s]);
        bfv[i] = *reinterpret_cast<const bf16x8*>((const char*)sB + offB[i][s]);
      }
#pragma unroll
      for (int i = 0; i < 2; i++)
#pragma unroll
        for (int j = 0; j < 2; j++)
          acc[i][j] = __builtin_amdgcn_mfma_f32_32x32x16_bf16(af[i], bfv[j], acc[i][j], 0, 0, 0);
    }
  }

  // ---- epilogue ----
  const int* mrow = (MODE == 2) ? (mask + (size_t)blockIdx.z * 2048) : nullptr;
  const bool vblock = (MODE == 1) && (blockIdx.x >= 16);  // QKV: n>=2048 is the V third

#pragma unroll
  for (int i = 0; i < 2; i++) {
    int gmb = blockIdx.y * 128 + wm + i * 32;
    float inv_r[16];
    if (MODE == 3) {
#pragma unroll
      for (int r = 0; r < 16; r++) {
        int row = (r & 3) + 8 * (r >> 2) + 4 * half;
        inv_r[r] = 1.0f / sums[(size_t)blockIdx.z * 2048 + gmb + row];
      }
    }
#pragma unroll
    for (int j = 0; j < 2; j++) {
      int gn = blockIdx.x * 128 + wn + j * 32 + r31;
      float bv = (MODE == 0 || MODE == 1) ? bias[gn] : 0.0f;
      if (MODE == 1 && vblock) {
        // write V^T: Vt[b][d][s], d = gn-2048, s = gmb+row. Per-lane quads of s
        // are contiguous -> ushort4 stores.
        int b = gmb >> 11;
        int sbase = gmb & 2047;
        int d = gn - 2048;
        unsigned short* vp = vt + (size_t)b * 1024 * 2048 + (size_t)d * 2048 + sbase + 4 * half;
#pragma unroll
        for (int qd = 0; qd < 4; qd++) {
          ushort4 o;
          o.x = f2bf(acc[i][j][4 * qd + 0] + bv);
          o.y = f2bf(acc[i][j][4 * qd + 1] + bv);
          o.z = f2bf(acc[i][j][4 * qd + 2] + bv);
          o.w = f2bf(acc[i][j][4 * qd + 3] + bv);
          *reinterpret_cast<ushort4*>(vp + 8 * qd) = o;
        }
      } else {
        bool msk = (MODE == 2) ? (mrow[gn] == 0) : false;
#pragma unroll
        for (int r = 0; r < 16; r++) {
          int row = (r & 3) + 8 * (r >> 2) + 4 * half;
          float val = acc[i][j][r] + bv;
          size_t off = (size_t)blockIdx.z * strideC + (size_t)(gmb + row) * ldc + gn;
          if (MODE == 2) {
            if (msk) val = -1e20f;
            val = __expf(val * 0.03125f);  // mask BEFORE 1/sqrt(1024) scale, per ref
            ((unsigned short*)Cv)[off] = f2bf(val);
          } else if (MODE == 3) {
            ((unsigned short*)Cv)[off] = f2bf(val * inv_r[r]);
          } else if (MODE == 1) {
            ((unsigned short*)Cv)[off] = f2bf(val);
          } else {
            ((float*)Cv)[off] = val;
          }
        }
      }
    }
  }
}

// ---------------- row sums of unnormalized exp weights, one row per wave ----------------
__global__ __launch_bounds__(256) void rowsum_kernel(const unsigned short* __restrict__ P,
                                                     float* __restrict__ sums) {
  int row = blockIdx.x * 4 + (threadIdx.x >> 6);
  int lane = threadIdx.x & 63;
  const uint4* pr = reinterpret_cast<const uint4*>(P + (size_t)row * 2048);
  float s = 0.f;
#pragma unroll
  for (int j = 0; j < 4; j++) {
    uint4 raw = pr[lane + j * 64];
    const unsigned* pw = (const unsigned*)&raw;
#pragma unroll
    for (int h = 0; h < 4; h++) { s += bf2f(pw[h] & 0xffff) + bf2f(pw[h] >> 16); }
  }
#pragma unroll
  for (int o = 32; o >= 1; o >>= 1) s += __shfl_xor(s, o, 64);
  if (lane == 0) sums[row] = s;
}

extern "C" void kernel_launch(void* const* d_in, const int* in_sizes, int n_in,
                              void* d_out, int out_size, void* d_ws, size_t ws_size,
                              hipStream_t stream) {
  const float* X = (const float*)d_in[0];
  const int* mask = (const int*)d_in[1];
  const float* W_in = (const float*)d_in[2];
  const float* b_in = (const float*)d_in[3];
  const float* W_out = (const float*)d_in[4];
  const float* b_out = (const float*)d_in[5];
  float* out = (float*)d_out;

  const int S = 2048, D = 1024;
  // ws layout (bytes):
  //   Xb  [8192x1024] bf16  16777216  (reused as Ob after QKV)
  //   Wib [3072x1024] bf16   6291456
  //   Wob [1024x1024] bf16   2097152
  //   QK  [8192x2048] bf16  33554432  (Q cols 0..1023, K cols 1024..2047; V goes to Vt)
  //   P   [4x2048x2048] bf16 33554432 (unnormalized exp weights)
  //   Vt  [4x1024x2048] bf16 16777216
  //   sums[8192] f32            32768   -> total 109084672
  char* w = (char*)d_ws;
  unsigned short* Xb  = (unsigned short*)w;
  unsigned short* Wib = (unsigned short*)(w + 16777216);
  unsigned short* Wob = (unsigned short*)(w + 16777216 + 6291456);
  unsigned short* QK  = (unsigned short*)(w + 25165824);
  unsigned short* P   = (unsigned short*)(w + 58720256);
  unsigned short* Vt  = (unsigned short*)(w + 92274688);
  float*          sums = (float*)(w + 109051904);
  unsigned short* Ob  = Xb;

  // one merged cast: X, W_in, W_out -> bf16 (outputs contiguous)
  cast_all_kernel<<<12288, 256, 0, stream>>>(X, W_in, W_out, Xb);

  // QKV = Xb @ W_in^T + b_in; Q,K -> QK[8192x2048], V -> Vt (transposed in epilogue)
  gemm_bt128<1><<<dim3(24, 64, 1), 256, 0, stream>>>(
      Xb, D, 0, Wib, D, 0, QK, 2048, 0, b_in, nullptr, nullptr, Vt, D);
  // P = exp(mask(Q K^T)/32)  [per batch 2048x2048]
  gemm_bt128<2><<<dim3(16, 16, 4), 256, 0, stream>>>(
      QK, 2048, (long)S * 2048, QK + 1024, 2048, (long)S * 2048,
      P, S, (long)S * S, nullptr, mask, nullptr, nullptr, D);
  // row sums of P
  rowsum_kernel<<<2048, 256, 0, stream>>>(P, sums);
  // O = (P @ Vt^T) / rowsum   [per batch 2048x1024] bf16
  gemm_bt128<3><<<dim3(8, 16, 4), 256, 0, stream>>>(
      P, S, (long)S * S, Vt, S, (long)D * S,
      Ob, D, (long)S * D, nullptr, nullptr, sums, nullptr, S);
  // out = O @ W_out^T + b_out  [8192x1024] fp32
  gemm_bt128<0><<<dim3(8, 64, 1), 256, 0, stream>>>(
      Ob, D, 0, Wob, D, 0, out, D, 0, b_out, nullptr, nullptr, nullptr, D);
}

// Round 8
// 292.240 us; speedup vs baseline: 1.9142x; 1.0297x over previous
//
#include <hip/hip_runtime.h>
#include <stdint.h>

#define AS1 __attribute__((address_space(1)))
#define AS3 __attribute__((address_space(3)))

typedef __bf16 bf16x8 __attribute__((ext_vector_type(8)));
typedef float f32x16 __attribute__((ext_vector_type(16)));

__device__ __forceinline__ unsigned short f2bf(float f) {
  unsigned u = __float_as_uint(f);
  u += 0x7FFF + ((u >> 16) & 1);   // round-to-nearest-even
  return (unsigned short)(u >> 16);
}
__device__ __forceinline__ float bf2f(unsigned short h) {
  return __uint_as_float(((unsigned)h) << 16);
}

// ---------------- merged fp32 -> bf16 cast for X, W_in, W_out ----------------
__global__ __launch_bounds__(256) void cast_all_kernel(const float* __restrict__ X,
                                                       const float* __restrict__ Wi,
                                                       const float* __restrict__ Wo,
                                                       unsigned short* __restrict__ out) {
  const int c1 = 2097152;            // X groups of 4
  const int c2 = 786432;             // W_in groups
  const int c3 = 262144;             // W_out groups
  int i = blockIdx.x * 256 + threadIdx.x;
  if (i >= c1 + c2 + c3) return;
  const float* src;
  int j = i;
  if (i < c1) src = X;
  else if (i < c1 + c2) { src = Wi; j = i - c1; }
  else { src = Wo; j = i - c1 - c2; }
  float4 v = reinterpret_cast<const float4*>(src)[j];
  ushort4 o;
  o.x = f2bf(v.x); o.y = f2bf(v.y); o.z = f2bf(v.z); o.w = f2bf(v.w);
  reinterpret_cast<ushort4*>(out)[i] = o;
}

// ---------------- GEMM-BT 128x128 (R3-proven core, fused epilogues) ----------------
// C[m][n] = sum_k A[m][k]*B[n][k]. BK=64, 4 waves of 2x2 32x32x16 MFMA,
// global_load_lds staging, XOR-8 chunk swizzle.
// MODE 0: fp32 out, +bias                                  (out-proj)
// MODE 1: bf16 out, +bias; blocks bx>=16 write V^T into vt (QKV + transpose)
// MODE 2: bf16 out = exp((mask? -1e20 : val)/32); row sums of fp32 exp
//         reduced cross-lane and atomically added into sums (QK^T + softmax top)
// MODE 3: bf16 out = val / sums[row]                       (PV + softmax normalize)
template<int MODE>
__global__ __launch_bounds__(256, 2) void gemm_bt128(
    const unsigned short* __restrict__ A, long lda, long strideA,
    const unsigned short* __restrict__ B, long ldb, long strideB,
    void* __restrict__ Cv, long ldc, long strideC,
    const float* __restrict__ bias, const int* __restrict__ mask,
    float* __restrict__ sums, unsigned short* __restrict__ vt, int K) {
  __shared__ unsigned short sA[128 * 64];
  __shared__ unsigned short sB[128 * 64];
  const int t = threadIdx.x;
  const int lane = t & 63;
  const int wave = t >> 6;

  const unsigned short* Ab = A + (size_t)blockIdx.z * strideA + (size_t)blockIdx.y * 128 * lda;
  const unsigned short* Bb = B + (size_t)blockIdx.z * strideB + (size_t)blockIdx.x * 128 * ldb;

  const int srow = t >> 3;
  const int schunk = (t & 7) ^ (srow & 7);
  const unsigned short* aptr = Ab + (size_t)srow * lda + schunk * 8;
  const unsigned short* bptr = Bb + (size_t)srow * ldb + schunk * 8;
  char* ldsA0 = (char*)&sA[0] + wave * 1024;
  char* ldsB0 = (char*)&sB[0] + wave * 1024;

  f32x16 acc[2][2];
#pragma unroll
  for (int i = 0; i < 2; i++)
#pragma unroll
    for (int j = 0; j < 2; j++)
#pragma unroll
      for (int r = 0; r < 16; r++) acc[i][j][r] = 0.f;

  const int wm = (wave >> 1) * 64;
  const int wn = (wave & 1) * 64;
  const int r31 = lane & 31;
  const int half = lane >> 5;
  const int swz = r31 & 7;

  int offA[2][4], offB[2][4];
#pragma unroll
  for (int i = 0; i < 2; i++)
#pragma unroll
    for (int s = 0; s < 4; s++) {
      offA[i][s] = (wm + i * 32 + r31) * 128 + (((2 * s + half) ^ swz) * 16);
      offB[i][s] = (wn + i * 32 + r31) * 128 + (((2 * s + half) ^ swz) * 16);
    }

  for (int k0 = 0; k0 < K; k0 += 64) {
    __syncthreads();
#pragma unroll
    for (int o = 0; o < 4; o++) {
      __builtin_amdgcn_global_load_lds((AS1 void*)(aptr + (size_t)o * 32 * lda + k0),
                                       (AS3 void*)(ldsA0 + o * 4096), 16, 0, 0);
      __builtin_amdgcn_global_load_lds((AS1 void*)(bptr + (size_t)o * 32 * ldb + k0),
                                       (AS3 void*)(ldsB0 + o * 4096), 16, 0, 0);
    }
    __syncthreads();
#pragma unroll
    for (int s = 0; s < 4; s++) {
      bf16x8 af[2], bfv[2];
#pragma unroll
      for (int i = 0; i < 2; i++) {
        af[i]  = *reinterpret_cast<const bf16x8*>((const char*)sA + offA[i][s]);
        bfv[i] = *reinterpret_cast<const bf16x8*>((const char*)sB + offB[i][s]);
      }
#pragma unroll
      for (int i = 0; i < 2; i++)
#pragma unroll
        for (int j = 0; j < 2; j++)
          acc[i][j] = __builtin_amdgcn_mfma_f32_32x32x16_bf16(af[i], bfv[j], acc[i][j], 0, 0, 0);
    }
  }

  // ---- epilogue ----
  const int* mrow = (MODE == 2) ? (mask + (size_t)blockIdx.z * 2048) : nullptr;
  const bool vblock = (MODE == 1) && (blockIdx.x >= 16);  // QKV: n>=2048 is the V third
  float rs[2][16];  // MODE 2: per-lane partial row sums (over this block's 128 cols)

#pragma unroll
  for (int i = 0; i < 2; i++) {
    int gmb = blockIdx.y * 128 + wm + i * 32;
    float inv_r[16];
    if (MODE == 3) {
#pragma unroll
      for (int r = 0; r < 16; r++) {
        int row = (r & 3) + 8 * (r >> 2) + 4 * half;
        inv_r[r] = 1.0f / sums[(size_t)blockIdx.z * 2048 + gmb + row];
      }
    }
    if (MODE == 2) {
#pragma unroll
      for (int r = 0; r < 16; r++) rs[i][r] = 0.f;
    }
#pragma unroll
    for (int j = 0; j < 2; j++) {
      int gn = blockIdx.x * 128 + wn + j * 32 + r31;
      float bv = (MODE == 0 || MODE == 1) ? bias[gn] : 0.0f;
      if (MODE == 1 && vblock) {
        // write V^T: Vt[b][d][s], d = gn-2048, s = gmb+row
        int b = gmb >> 11;
        int sbase = gmb & 2047;
        int d = gn - 2048;
        unsigned short* vp = vt + (size_t)b * 1024 * 2048 + (size_t)d * 2048 + sbase + 4 * half;
#pragma unroll
        for (int qd = 0; qd < 4; qd++) {
          ushort4 o;
          o.x = f2bf(acc[i][j][4 * qd + 0] + bv);
          o.y = f2bf(acc[i][j][4 * qd + 1] + bv);
          o.z = f2bf(acc[i][j][4 * qd + 2] + bv);
          o.w = f2bf(acc[i][j][4 * qd + 3] + bv);
          *reinterpret_cast<ushort4*>(vp + 8 * qd) = o;
        }
      } else {
        bool msk = (MODE == 2) ? (mrow[gn] == 0) : false;
#pragma unroll
        for (int r = 0; r < 16; r++) {
          int row = (r & 3) + 8 * (r >> 2) + 4 * half;
          float val = acc[i][j][r] + bv;
          size_t off = (size_t)blockIdx.z * strideC + (size_t)(gmb + row) * ldc + gn;
          if (MODE == 2) {
            if (msk) val = -1e20f;
            val = __expf(val * 0.03125f);  // mask BEFORE 1/sqrt(1024) scale, per ref
            rs[i][r] += val;
            ((unsigned short*)Cv)[off] = f2bf(val);
          } else if (MODE == 3) {
            ((unsigned short*)Cv)[off] = f2bf(val * inv_r[r]);
          } else if (MODE == 1) {
            ((unsigned short*)Cv)[off] = f2bf(val);
          } else {
            ((float*)Cv)[off] = val;
          }
        }
      }
    }
  }

  if (MODE == 2) {
    // reduce rs over the 32 column-lanes (r31), then one atomicAdd per row.
    float* srow = sums + (size_t)blockIdx.z * 2048;
#pragma unroll
    for (int i = 0; i < 2; i++) {
      int gmb = blockIdx.y * 128 + wm + i * 32;
#pragma unroll
      for (int r = 0; r < 16; r++) {
        float v = rs[i][r];
#pragma unroll
        for (int o = 16; o >= 1; o >>= 1) v += __shfl_xor(v, o, 64);
        if (r31 == 0) {
          int row = (r & 3) + 8 * (r >> 2) + 4 * half;
          atomicAdd(&srow[gmb + row], v);
        }
      }
    }
  }
}

extern "C" void kernel_launch(void* const* d_in, const int* in_sizes, int n_in,
                              void* d_out, int out_size, void* d_ws, size_t ws_size,
                              hipStream_t stream) {
  const float* X = (const float*)d_in[0];
  const int* mask = (const int*)d_in[1];
  const float* W_in = (const float*)d_in[2];
  const float* b_in = (const float*)d_in[3];
  const float* W_out = (const float*)d_in[4];
  const float* b_out = (const float*)d_in[5];
  float* out = (float*)d_out;

  const int S = 2048, D = 1024;
  // ws layout (bytes):
  //   Xb  [8192x1024] bf16  16777216  (reused as Ob after QKV)
  //   Wib [3072x1024] bf16   6291456
  //   Wob [1024x1024] bf16   2097152
  //   QK  [8192x2048] bf16  33554432  (Q cols 0..1023, K cols 1024..2047)
  //   P   [4x2048x2048] bf16 33554432 (unnormalized exp weights)
  //   Vt  [4x1024x2048] bf16 16777216
  //   sums[8192] f32            32768
  char* w = (char*)d_ws;
  unsigned short* Xb  = (unsigned short*)w;
  unsigned short* Wib = (unsigned short*)(w + 16777216);
  unsigned short* Wob = (unsigned short*)(w + 16777216 + 6291456);
  unsigned short* QK  = (unsigned short*)(w + 25165824);
  unsigned short* P   = (unsigned short*)(w + 58720256);
  unsigned short* Vt  = (unsigned short*)(w + 92274688);
  float*          sums = (float*)(w + 109051904);
  unsigned short* Ob  = Xb;

  // zero the row-sum accumulators (ws is re-poisoned before every call)
  hipMemsetAsync(sums, 0, 8192 * sizeof(float), stream);

  // one merged cast: X, W_in, W_out -> bf16 (outputs contiguous)
  cast_all_kernel<<<12288, 256, 0, stream>>>(X, W_in, W_out, Xb);

  // QKV = Xb @ W_in^T + b_in; Q,K -> QK[8192x2048], V -> Vt (transposed in epilogue)
  gemm_bt128<1><<<dim3(24, 64, 1), 256, 0, stream>>>(
      Xb, D, 0, Wib, D, 0, QK, 2048, 0, b_in, nullptr, nullptr, Vt, D);
  // P = exp(mask(Q K^T)/32); sums += row sums of fp32 exp  [per batch 2048x2048]
  gemm_bt128<2><<<dim3(16, 16, 4), 256, 0, stream>>>(
      QK, 2048, (long)S * 2048, QK + 1024, 2048, (long)S * 2048,
      P, S, (long)S * S, nullptr, mask, sums, nullptr, D);
  // O = (P @ Vt^T) / sums   [per batch 2048x1024] bf16
  gemm_bt128<3><<<dim3(8, 16, 4), 256, 0, stream>>>(
      P, S, (long)S * S, Vt, S, (long)D * S,
      Ob, D, (long)S * D, nullptr, nullptr, sums, nullptr, S);
  // out = O @ W_out^T + b_out  [8192x1024] fp32
  gemm_bt128<0><<<dim3(8, 64, 1), 256, 0, stream>>>(
      Ob, D, 0, Wob, D, 0, out, D, 0, b_out, nullptr, nullptr, nullptr, D);
}